// Round 1
// 563.685 us; speedup vs baseline: 1.0138x; 1.0138x over previous
//
#include <hip/hip_runtime.h>
#include <hip/hip_bf16.h>

#define Bb   2
#define Ss   2048
#define Dd   2048
#define Hh   16
#define KVHh 4
#define HDd  128

typedef __bf16 bf16x8 __attribute__((ext_vector_type(8)));
typedef float f32x4 __attribute__((ext_vector_type(4)));

__device__ __forceinline__ unsigned short f2bf(float f) {
    unsigned u = __float_as_uint(f);
    unsigned r = (u + 0x7FFFu + ((u >> 16) & 1u)) >> 16;   // RNE
    return (unsigned short)r;
}
__device__ __forceinline__ float bfu2f(unsigned short u) {
    return __uint_as_float(((unsigned)u) << 16);
}

// async global->LDS, 16B per lane; lds base must be wave-uniform
#define GLOAD16(g, l) __builtin_amdgcn_global_load_lds( \
    (const __attribute__((address_space(1))) unsigned int*)(g), \
    (__attribute__((address_space(3))) unsigned int*)(l), 16, 0, 0)

// fp32 -> bf16 elementwise, 4 elems/thread
__global__ __launch_bounds__(256)
void cast_bf16(const float* __restrict__ X, unsigned short* __restrict__ Y)
{
    int idx = blockIdx.x * 256 + threadIdx.x;
    float4 v = reinterpret_cast<const float4*>(X)[idx];
    ushort4 o;
    o.x = f2bf(v.x); o.y = f2bf(v.y); o.z = f2bf(v.z); o.w = f2bf(v.w);
    reinterpret_cast<ushort4*>(Y)[idx] = o;
}

// W[K,N] fp32 -> WT[N,K] bf16
__global__ __launch_bounds__(256)
void wt_cast(const float* __restrict__ W, unsigned short* __restrict__ WT,
             int K, int N)
{
    __shared__ float tile[32][33];
    int k0 = blockIdx.x * 32, n0 = blockIdx.y * 32;
    int tx = threadIdx.x & 31, ty = threadIdx.x >> 5;   // 32 x 8
    #pragma unroll
    for (int i = 0; i < 32; i += 8)
        tile[ty + i][tx] = W[(size_t)(k0 + ty + i) * N + n0 + tx];
    __syncthreads();
    #pragma unroll
    for (int i = 0; i < 32; i += 8)
        WT[(size_t)(n0 + ty + i) * K + k0 + tx] = f2bf(tile[tx][ty + i]);
}

// C[M,N] = A[M,K] @ BT[N,K]^T, bf16 in, fp32 accumulate, fp32 or bf16 out.
// 128x128 tile, BK=32, 4 waves (2x2 of 64x64), global_load_lds staging.
template<bool BF16OUT>
__global__ __launch_bounds__(256)
void gemm_bt(const unsigned short* __restrict__ A,
             const unsigned short* __restrict__ BT,
             void* __restrict__ Cv, int M, int N, int K)
{
    __shared__ __align__(16) unsigned short sA[128 * 32];
    __shared__ __align__(16) unsigned short sB[128 * 32];
    const int tid  = threadIdx.x;
    const int wave = tid >> 6;
    const int lane = tid & 63;
    const int m    = lane & 15;
    const int quad = lane >> 4;
    const int wm   = wave >> 1, wn = wave & 1;
    const int m0   = blockIdx.y * 128, n0 = blockIdx.x * 128;

    const int srow = tid >> 2;          // 0..63
    const int skg  = (tid & 3) * 8;     // k-group *8 elems

    f32x4 acc[4][4];
    #pragma unroll
    for (int r = 0; r < 4; ++r)
        #pragma unroll
        for (int c = 0; c < 4; ++c) acc[r][c] = (f32x4){0.f, 0.f, 0.f, 0.f};

    const unsigned short* pa = A  + (size_t)(m0 + srow) * K + skg;
    const unsigned short* pb = BT + (size_t)(n0 + srow) * K + skg;
    unsigned short* la = &sA[wave * 16 * 32];   // wave-uniform LDS base
    unsigned short* lb = &sB[wave * 16 * 32];

    for (int k0 = 0; k0 < K; k0 += 32) {
        GLOAD16(pa + k0, la);
        GLOAD16(pa + (size_t)64 * K + k0, la + 64 * 32);
        GLOAD16(pb + k0, lb);
        GLOAD16(pb + (size_t)64 * K + k0, lb + 64 * 32);
        __syncthreads();
        bf16x8 af[4], bfr[4];
        #pragma unroll
        for (int r = 0; r < 4; ++r)
            af[r] = *reinterpret_cast<const bf16x8*>(
                &sA[(wm * 64 + r * 16 + m) * 32 + quad * 8]);
        #pragma unroll
        for (int c = 0; c < 4; ++c)
            bfr[c] = *reinterpret_cast<const bf16x8*>(
                &sB[(wn * 64 + c * 16 + m) * 32 + quad * 8]);
        #pragma unroll
        for (int r = 0; r < 4; ++r)
            #pragma unroll
            for (int c = 0; c < 4; ++c)
                acc[r][c] = __builtin_amdgcn_mfma_f32_16x16x32_bf16(
                    af[r], bfr[c], acc[r][c], 0, 0, 0);
        __syncthreads();
    }
    // C/D layout: row = quad*4 + e, col = m
    #pragma unroll
    for (int r = 0; r < 4; ++r)
        #pragma unroll
        for (int c = 0; c < 4; ++c)
            #pragma unroll
            for (int e = 0; e < 4; ++e) {
                size_t row = m0 + wm * 64 + r * 16 + quad * 4 + e;
                size_t col = n0 + wn * 64 + c * 16 + m;
                if (BF16OUT)
                    ((unsigned short*)Cv)[row * N + col] = f2bf(acc[r][c][e]);
                else
                    ((float*)Cv)[row * N + col] = acc[r][c][e];
            }
}

// In-place RoPE on bf16 X, rows of `rowstride`, head slice h*128.
__global__ __launch_bounds__(256)
void rope_bf(unsigned short* __restrict__ X, const float* __restrict__ cosT,
             const float* __restrict__ sinT, int nhshift, int rowstride,
             float scale, int total)
{
    int idx = blockIdx.x * 256 + threadIdx.x;
    if (idx >= total) return;
    int i   = idx & 63;
    int rh  = idx >> 6;                  // (b*S+s)*nh + h
    int row = rh >> nhshift;             // b*S + s
    int h   = rh & ((1 << nhshift) - 1);
    int s   = row & (Ss - 1);
    unsigned short* xp = X + (size_t)row * rowstride + h * HDd;
    float x1 = bfu2f(xp[i]);
    float x2 = bfu2f(xp[i + 64]);
    float c1 = cosT[s * HDd + i];
    float c2 = cosT[s * HDd + i + 64];
    float s1 = sinT[s * HDd + i];
    float s2 = sinT[s * HDd + i + 64];
    xp[i]      = f2bf((x1 * c1 - x2 * s1) * scale);
    xp[i + 64] = f2bf((x2 * c2 + x1 * s2) * scale);
}

// V (cols 512.. of KVraw [B*S,1024] bf16) -> VT [B,KVH,128,S] bf16
__global__ __launch_bounds__(256)
void vt_cast_bf(const unsigned short* __restrict__ KV,
                unsigned short* __restrict__ VT)
{
    __shared__ unsigned short tile[32][34];
    int st = blockIdx.x * 32, dt = blockIdx.y * 32;
    int bk = blockIdx.z;
    int b = bk >> 2, kvh = bk & 3;
    int tx = threadIdx.x & 31, ty = threadIdx.x >> 5;   // 32 x 8
    #pragma unroll
    for (int i = 0; i < 32; i += 8)
        tile[ty + i][tx] = KV[(size_t)(b * Ss + st + ty + i) * 1024 + 512 + kvh * HDd + dt + tx];
    __syncthreads();
    #pragma unroll
    for (int i = 0; i < 32; i += 8)
        VT[(((size_t)b * KVHh + kvh) * HDd + dt + ty + i) * Ss + st + tx] =
            tile[tx][ty + i];
}

// Flash attention, max-free softmax (scores bounded; exp sums << fp32 range).
// One wave per block, __launch_bounds__(64,1). Each wave processes the
// balanced q-tile pair {qt, 127-qt} (~65 k-tiles each -> no causal tail).
//
// Round-6: software-pipelined k-tile loop. Latency-bound diagnosis (MfmaUtil
// 5.3%, VALUBusy 14%, HBM 6%, ~9.7K cyc/iter vs ~350 cyc compute): loads for
// tile t were issued and AWAITED inside iteration t. Now tile t+1's K/alibi/V
// are prefetched into a second register buffer set while tile t computes,
// giving every load a full iteration (~350+ cyc) of latency cover. Named A/B
// buffer sets (two-body loop) keep all indexing compile-time-constant so
// nothing spills to scratch. VGPR ~230 -> still 2 waves/SIMD, the same
// occupancy as before (2048 waves = 8/CU), so nothing is lost to pressure.
__global__ __launch_bounds__(64, 1)
void flash_attn(const unsigned short* __restrict__ Qb,   // [B*S,2048] bf16
                const unsigned short* __restrict__ KVb,  // [B*S,1024] bf16 (K part)
                const unsigned short* __restrict__ VT,   // [B,KVH,128,S] bf16
                const float* __restrict__ alibi,         // [B,S,S]
                const float* __restrict__ amask,         // [B,S]
                unsigned short* __restrict__ ctx)        // [B*S,2048] bf16
{
    __shared__ unsigned short s_p[16][56];   // P rows padded to 112B (16B-aligned)
    const int lane = threadIdx.x;
    const int m    = lane & 15;
    const int quad = lane >> 4;

    const int h   = blockIdx.y;
    const int b   = blockIdx.z;
    const int kvh = h >> 2;

    const unsigned short* vt0 = VT + ((size_t)b * KVHh + kvh) * HDd * Ss;
    const float* amrow = amask + (size_t)b * Ss;

    const int qts[2] = { (int)blockIdx.x, 127 - (int)blockIdx.x };

    #pragma unroll 1
    for (int pi = 0; pi < 2; ++pi) {
        const int q0 = qts[pi] * 16;

        bf16x8 qa[4];
        {
            const unsigned short* qrow = Qb + (size_t)(b * Ss + q0 + m) * Dd + h * HDd;
            #pragma unroll
            for (int c = 0; c < 4; ++c)
                qa[c] = *reinterpret_cast<const bf16x8*>(qrow + c * 32 + quad * 8);
        }

        f32x4 o[8];
        #pragma unroll
        for (int f = 0; f < 8; ++f) o[f] = (f32x4){0.f, 0.f, 0.f, 0.f};
        float lrow[4] = {0.f, 0.f, 0.f, 0.f};

        const float* arow = alibi + ((size_t)b * Ss + q0 + quad * 4) * Ss;
        const unsigned short* krow = KVb + (size_t)(b * Ss + m) * 1024 + kvh * HDd;

        const int ntiles = (q0 + 47) >> 5;      // keys 0..q0+15 (>= 1)

        // double-buffered per-tile register state
        bf16x8 kA0[4], kA1[4], vA[8]; float aA0[4], aA1[4], amA0, amA1;
        bf16x8 kB0[4], kB1[4], vB[8]; float aB0[4], aB1[4], amB0, amB1;

        // issue all loads for tile kt into the given buffer set
        auto LD = [&](int kt, bf16x8 (&k0v)[4], bf16x8 (&k1v)[4], bf16x8 (&vv)[8],
                      float (&a0v)[4], float (&a1v)[4], float &am0v, float &am1v) {
            const int k0 = kt * 32;
            const unsigned short* kr0 = krow + (size_t)k0 * 1024;
            const unsigned short* kr1 = kr0 + (size_t)16 * 1024;
            #pragma unroll
            for (int c = 0; c < 4; ++c) {
                k0v[c] = *reinterpret_cast<const bf16x8*>(kr0 + c * 32 + quad * 8);
                k1v[c] = *reinterpret_cast<const bf16x8*>(kr1 + c * 32 + quad * 8);
            }
            #pragma unroll
            for (int r = 0; r < 4; ++r) {
                a0v[r] = arow[(size_t)r * Ss + k0 + m];
                a1v[r] = arow[(size_t)r * Ss + k0 + 16 + m];
            }
            am0v = amrow[k0 + m];
            am1v = amrow[k0 + 16 + m];
            #pragma unroll
            for (int f = 0; f < 8; ++f)
                vv[f] = *reinterpret_cast<const bf16x8*>(
                    vt0 + (size_t)(f * 16 + m) * Ss + k0 + quad * 8);
        };

        // full compute for tile kt out of the given buffer set
        auto CMP = [&](int kt, bf16x8 (&k0v)[4], bf16x8 (&k1v)[4], bf16x8 (&vv)[8],
                       float (&a0v)[4], float (&a1v)[4], float &am0v, float &am1v) {
            const int k0 = kt * 32;
            f32x4 s0 = {0.f, 0.f, 0.f, 0.f}, s1 = {0.f, 0.f, 0.f, 0.f};
            #pragma unroll
            for (int c = 0; c < 4; ++c) {
                s0 = __builtin_amdgcn_mfma_f32_16x16x32_bf16(qa[c], k0v[c], s0, 0, 0, 0);
                s1 = __builtin_amdgcn_mfma_f32_16x16x32_bf16(qa[c], k1v[c], s1, 0, 0, 0);
            }
            // max-free softmax: p = exp(s + bias); no cross-lane work in loop
            #pragma unroll
            for (int r = 0; r < 4; ++r) {
                const int qi = q0 + quad * 4 + r;
                float x0 = s0[r] + a0v[r] + am0v;
                float x1 = s1[r] + a1v[r] + am1v;
                x0 = (k0 + m      <= qi) ? x0 : -1e30f;
                x1 = (k0 + 16 + m <= qi) ? x1 : -1e30f;
                const float p0 = __expf(x0);
                const float p1 = __expf(x1);
                lrow[r] += p0 + p1;
                s_p[quad * 4 + r][m]      = f2bf(p0);
                s_p[quad * 4 + r][16 + m] = f2bf(p1);
            }
            // P: C-layout -> A-layout via LDS (same-wave DS is in-order)
            __builtin_amdgcn_wave_barrier();
            const bf16x8 pa = *reinterpret_cast<const bf16x8*>(&s_p[m][quad * 8]);
            __builtin_amdgcn_wave_barrier();
            #pragma unroll
            for (int f = 0; f < 8; ++f)
                o[f] = __builtin_amdgcn_mfma_f32_16x16x32_bf16(pa, vv[f], o[f], 0, 0, 0);
        };

        // prologue: tile 0 into A
        LD(0, kA0, kA1, vA, aA0, aA1, amA0, amA1);
        int kt = 0;
        while (true) {
            // prefetch t+1 into B, compute t out of A
            if (kt + 1 < ntiles) LD(kt + 1, kB0, kB1, vB, aB0, aB1, amB0, amB1);
            CMP(kt, kA0, kA1, vA, aA0, aA1, amA0, amA1);
            if (++kt >= ntiles) break;
            // prefetch t+1 into A, compute t out of B
            if (kt + 1 < ntiles) LD(kt + 1, kA0, kA1, vA, aA0, aA1, amA0, amA1);
            CMP(kt, kB0, kB1, vB, aB0, aB1, amB0, amB1);
            if (++kt >= ntiles) break;
        }

        // reduce l across the 16 columns held by lanes of each quad-row group
        float inv[4];
        #pragma unroll
        for (int r = 0; r < 4; ++r) {
            float l = lrow[r];
            l += __shfl_xor(l, 1, 64);
            l += __shfl_xor(l, 2, 64);
            l += __shfl_xor(l, 4, 64);
            l += __shfl_xor(l, 8, 64);
            inv[r] = 1.f / l;
        }
        #pragma unroll
        for (int f = 0; f < 8; ++f)
            #pragma unroll
            for (int r = 0; r < 4; ++r)
                ctx[(size_t)(b * Ss + q0 + quad * 4 + r) * Dd + h * HDd + f * 16 + m] =
                    f2bf(o[f][r] * inv[r]);
    }
}

extern "C" void kernel_launch(void* const* d_in, const int* in_sizes, int n_in,
                              void* d_out, int out_size, void* d_ws, size_t ws_size,
                              hipStream_t stream) {
    const float* hidden = (const float*)d_in[0];
    const float* cosT   = (const float*)d_in[1];
    const float* sinT   = (const float*)d_in[2];
    const float* alibi  = (const float*)d_in[3];
    const float* amask  = (const float*)d_in[4];
    const float* wq     = (const float*)d_in[5];
    const float* wk     = (const float*)d_in[6];
    const float* wv     = (const float*)d_in[7];
    const float* wo     = (const float*)d_in[8];
    float* out = (float*)d_out;

    char* ws = (char*)d_ws;
    unsigned short* Abf   = (unsigned short*)(ws);              // 16,777,216
    unsigned short* wqT   = (unsigned short*)(ws + 16777216);   //  8,388,608
    unsigned short* kvT   = (unsigned short*)(ws + 25165824);   //  4,194,304
    unsigned short* woT   = (unsigned short*)(ws + 29360128);   //  8,388,608
    unsigned short* Qraw  = (unsigned short*)(ws + 37748736);   // 16,777,216
    unsigned short* KVraw = (unsigned short*)(ws + 54525952);   //  8,388,608
    unsigned short* VT    = (unsigned short*)(ws + 62914560);   //  4,194,304
    unsigned short* Ctx   = (unsigned short*)(ws + 67108864);   // 16,777,216
    // total: 83,886,080 B

    const int M = Bb * Ss;  // 4096

    cast_bf16<<<(M * Dd / 4) / 256, 256, 0, stream>>>(hidden, Abf);
    wt_cast<<<dim3(64, 64), 256, 0, stream>>>(wq, wqT, Dd, Dd);
    wt_cast<<<dim3(64, 16), 256, 0, stream>>>(wk, kvT, Dd, 512);
    wt_cast<<<dim3(64, 16), 256, 0, stream>>>(wv, kvT + (size_t)512 * Dd, Dd, 512);
    wt_cast<<<dim3(64, 64), 256, 0, stream>>>(wo, woT, Dd, Dd);

    gemm_bt<true><<<dim3(Dd / 128, M / 128), 256, 0, stream>>>(Abf, wqT, Qraw, M, Dd, Dd);
    gemm_bt<true><<<dim3(1024 / 128, M / 128), 256, 0, stream>>>(Abf, kvT, KVraw, M, 1024, Dd);

    const float scale = 0.08838834764831845f;  // 1/sqrt(128), folded into Q
    int totQ = Bb * Ss * Hh * 64;
    rope_bf<<<totQ / 256, 256, 0, stream>>>(Qraw, cosT, sinT, 4, Dd, scale, totQ);
    int totK = Bb * Ss * KVHh * 64;
    rope_bf<<<totK / 256, 256, 0, stream>>>(KVraw, cosT, sinT, 2, 1024, 1.0f, totK);

    vt_cast_bf<<<dim3(Ss / 32, HDd / 32, Bb * KVHh), 256, 0, stream>>>(KVraw, VT);

    flash_attn<<<dim3(64, Hh, Bb), 64, 0, stream>>>(Qraw, KVraw, VT, alibi, amask, Ctx);

    gemm_bt<false><<<dim3(Dd / 128, M / 128), 256, 0, stream>>>(Ctx, woT, out, M, Dd, Dd);
}

// Round 2
// 433.740 us; speedup vs baseline: 1.3175x; 1.2996x over previous
//
#include <hip/hip_runtime.h>
#include <hip/hip_bf16.h>

#define Bb   2
#define Ss   2048
#define Dd   2048
#define Hh   16
#define KVHh 4
#define HDd  128

typedef __bf16 bf16x8 __attribute__((ext_vector_type(8)));
typedef float f32x4 __attribute__((ext_vector_type(4)));

__device__ __forceinline__ unsigned short f2bf(float f) {
    unsigned u = __float_as_uint(f);
    unsigned r = (u + 0x7FFFu + ((u >> 16) & 1u)) >> 16;   // RNE
    return (unsigned short)r;
}
__device__ __forceinline__ float bfu2f(unsigned short u) {
    return __uint_as_float(((unsigned)u) << 16);
}

// async global->LDS, 16B per lane; lds base must be wave-uniform
#define GLOAD16(g, l) __builtin_amdgcn_global_load_lds( \
    (const __attribute__((address_space(1))) unsigned int*)(g), \
    (__attribute__((address_space(3))) unsigned int*)(l), 16, 0, 0)

// fp32 -> bf16 elementwise, 4 elems/thread
__global__ __launch_bounds__(256)
void cast_bf16(const float* __restrict__ X, unsigned short* __restrict__ Y)
{
    int idx = blockIdx.x * 256 + threadIdx.x;
    float4 v = reinterpret_cast<const float4*>(X)[idx];
    ushort4 o;
    o.x = f2bf(v.x); o.y = f2bf(v.y); o.z = f2bf(v.z); o.w = f2bf(v.w);
    reinterpret_cast<ushort4*>(Y)[idx] = o;
}

// W[K,N] fp32 -> WT[N,K] bf16
__global__ __launch_bounds__(256)
void wt_cast(const float* __restrict__ W, unsigned short* __restrict__ WT,
             int K, int N)
{
    __shared__ float tile[32][33];
    int k0 = blockIdx.x * 32, n0 = blockIdx.y * 32;
    int tx = threadIdx.x & 31, ty = threadIdx.x >> 5;   // 32 x 8
    #pragma unroll
    for (int i = 0; i < 32; i += 8)
        tile[ty + i][tx] = W[(size_t)(k0 + ty + i) * N + n0 + tx];
    __syncthreads();
    #pragma unroll
    for (int i = 0; i < 32; i += 8)
        WT[(size_t)(n0 + ty + i) * K + k0 + tx] = f2bf(tile[tx][ty + i]);
}

// C[M,N] = A[M,K] @ BT[N,K]^T, bf16 in, fp32 accumulate, fp32 or bf16 out.
// 128x128 tile, BK=32, 4 waves (2x2 of 64x64), global_load_lds staging.
template<bool BF16OUT>
__global__ __launch_bounds__(256)
void gemm_bt(const unsigned short* __restrict__ A,
             const unsigned short* __restrict__ BT,
             void* __restrict__ Cv, int M, int N, int K)
{
    __shared__ __align__(16) unsigned short sA[128 * 32];
    __shared__ __align__(16) unsigned short sB[128 * 32];
    const int tid  = threadIdx.x;
    const int wave = tid >> 6;
    const int lane = tid & 63;
    const int m    = lane & 15;
    const int quad = lane >> 4;
    const int wm   = wave >> 1, wn = wave & 1;
    const int m0   = blockIdx.y * 128, n0 = blockIdx.x * 128;

    const int srow = tid >> 2;          // 0..63
    const int skg  = (tid & 3) * 8;     // k-group *8 elems

    f32x4 acc[4][4];
    #pragma unroll
    for (int r = 0; r < 4; ++r)
        #pragma unroll
        for (int c = 0; c < 4; ++c) acc[r][c] = (f32x4){0.f, 0.f, 0.f, 0.f};

    const unsigned short* pa = A  + (size_t)(m0 + srow) * K + skg;
    const unsigned short* pb = BT + (size_t)(n0 + srow) * K + skg;
    unsigned short* la = &sA[wave * 16 * 32];   // wave-uniform LDS base
    unsigned short* lb = &sB[wave * 16 * 32];

    for (int k0 = 0; k0 < K; k0 += 32) {
        GLOAD16(pa + k0, la);
        GLOAD16(pa + (size_t)64 * K + k0, la + 64 * 32);
        GLOAD16(pb + k0, lb);
        GLOAD16(pb + (size_t)64 * K + k0, lb + 64 * 32);
        __syncthreads();
        bf16x8 af[4], bfr[4];
        #pragma unroll
        for (int r = 0; r < 4; ++r)
            af[r] = *reinterpret_cast<const bf16x8*>(
                &sA[(wm * 64 + r * 16 + m) * 32 + quad * 8]);
        #pragma unroll
        for (int c = 0; c < 4; ++c)
            bfr[c] = *reinterpret_cast<const bf16x8*>(
                &sB[(wn * 64 + c * 16 + m) * 32 + quad * 8]);
        #pragma unroll
        for (int r = 0; r < 4; ++r)
            #pragma unroll
            for (int c = 0; c < 4; ++c)
                acc[r][c] = __builtin_amdgcn_mfma_f32_16x16x32_bf16(
                    af[r], bfr[c], acc[r][c], 0, 0, 0);
        __syncthreads();
    }
    // C/D layout: row = quad*4 + e, col = m
    #pragma unroll
    for (int r = 0; r < 4; ++r)
        #pragma unroll
        for (int c = 0; c < 4; ++c)
            #pragma unroll
            for (int e = 0; e < 4; ++e) {
                size_t row = m0 + wm * 64 + r * 16 + quad * 4 + e;
                size_t col = n0 + wn * 64 + c * 16 + m;
                if (BF16OUT)
                    ((unsigned short*)Cv)[row * N + col] = f2bf(acc[r][c][e]);
                else
                    ((float*)Cv)[row * N + col] = acc[r][c][e];
            }
}

// In-place RoPE on bf16 X, rows of `rowstride`, head slice h*128.
__global__ __launch_bounds__(256)
void rope_bf(unsigned short* __restrict__ X, const float* __restrict__ cosT,
             const float* __restrict__ sinT, int nhshift, int rowstride,
             float scale, int total)
{
    int idx = blockIdx.x * 256 + threadIdx.x;
    if (idx >= total) return;
    int i   = idx & 63;
    int rh  = idx >> 6;                  // (b*S+s)*nh + h
    int row = rh >> nhshift;             // b*S + s
    int h   = rh & ((1 << nhshift) - 1);
    int s   = row & (Ss - 1);
    unsigned short* xp = X + (size_t)row * rowstride + h * HDd;
    float x1 = bfu2f(xp[i]);
    float x2 = bfu2f(xp[i + 64]);
    float c1 = cosT[s * HDd + i];
    float c2 = cosT[s * HDd + i + 64];
    float s1 = sinT[s * HDd + i];
    float s2 = sinT[s * HDd + i + 64];
    xp[i]      = f2bf((x1 * c1 - x2 * s1) * scale);
    xp[i + 64] = f2bf((x2 * c2 + x1 * s2) * scale);
}

// V (cols 512.. of KVraw [B*S,1024] bf16) -> VT [B,KVH,128,S] bf16
__global__ __launch_bounds__(256)
void vt_cast_bf(const unsigned short* __restrict__ KV,
                unsigned short* __restrict__ VT)
{
    __shared__ unsigned short tile[32][34];
    int st = blockIdx.x * 32, dt = blockIdx.y * 32;
    int bk = blockIdx.z;
    int b = bk >> 2, kvh = bk & 3;
    int tx = threadIdx.x & 31, ty = threadIdx.x >> 5;   // 32 x 8
    #pragma unroll
    for (int i = 0; i < 32; i += 8)
        tile[ty + i][tx] = KV[(size_t)(b * Ss + st + ty + i) * 1024 + 512 + kvh * HDd + dt + tx];
    __syncthreads();
    #pragma unroll
    for (int i = 0; i < 32; i += 8)
        VT[(((size_t)b * KVHh + kvh) * HDd + dt + ty + i) * Ss + st + tx] =
            tile[tx][ty + i];
}

// Flash attention, max-free softmax (scores bounded; exp sums << fp32 range).
//
// Round-7 structure: one block = 4 waves = the 4 heads of one KV group, all
// on the same q-tile pair {qt, 127-qt}. K, V AND alibi (head-independent!)
// are shared: K/V staged once per block into double-buffered LDS via
// global_load_lds (zero VGPR cost, can't be sunk by the scheduler — fixes
// round-6's collapse where the register pipeline halved occupancy for no
// gain). One __syncthreads per k-tile: stage t+1 issued at top, drain at
// bottom -> full iteration of compute covers the staging latency.
//
// K LDS tile [32 keys][256B] is XOR-swizzled (byte ^= (row&7)<<4) to reach
// the ds_read_b128 bank floor; swizzle is pre-applied to the per-lane GLOBAL
// source address (global_load_lds writes linearly — rule: both sides or
// neither). V tile [128 d][64B] read at (f*16+m)*64+quad*16 is already at
// the bank floor -> linear.
__global__ __launch_bounds__(256, 2)
void flash_attn(const unsigned short* __restrict__ Qb,   // [B*S,2048] bf16
                const unsigned short* __restrict__ KVb,  // [B*S,1024] bf16 (K part)
                const unsigned short* __restrict__ VT,   // [B,KVH,128,S] bf16
                const float* __restrict__ alibi,         // [B,S,S]
                const float* __restrict__ amask,         // [B,S]
                unsigned short* __restrict__ ctx)        // [B*S,2048] bf16
{
    __shared__ __align__(16) unsigned short kbuf[2][32 * 128];  // 8KB/buf, row=key, 256B/row, swizzled
    __shared__ __align__(16) unsigned short vbuf[2][128 * 32];  // 8KB/buf, row=d, 64B/row, linear
    __shared__ unsigned short s_p[4][16][56];                    // per-wave P scratch (112B rows)

    const int tid  = threadIdx.x;
    const int w    = tid >> 6;
    const int lane = tid & 63;
    const int m    = lane & 15;
    const int quad = lane >> 4;

    const int kvh = blockIdx.y;
    const int b   = blockIdx.z;
    const int h   = kvh * 4 + w;        // this wave's head

    const unsigned short* vt0 = VT + ((size_t)b * KVHh + kvh) * HDd * Ss;
    const float* amrow = amask + (size_t)b * Ss;

    // staging geometry (256 threads cooperate; dest is linear in thread order)
    const int krow_s = tid >> 4;                                  // K row 0..15 (+16 on issue 1)
    const int koff_b = ((tid & 15) * 16) ^ ((krow_s & 7) << 4);   // pre-swizzled src byte in row
    const int vrow_s = tid >> 2;                                  // V row 0..63 (+64 on issue 1)
    const int vchk   = tid & 3;
    const int dstw   = w * 512;                                   // wave's 1KB stripe (ushorts)

    const unsigned short* kgbase = KVb + (size_t)b * Ss * 1024 + kvh * HDd;

    const int qts[2] = { (int)blockIdx.x, 127 - (int)blockIdx.x };

    #pragma unroll 1
    for (int pi = 0; pi < 2; ++pi) {
        const int q0 = qts[pi] * 16;

        bf16x8 qa[4];
        {
            const unsigned short* qrow = Qb + (size_t)(b * Ss + q0 + m) * Dd + h * HDd;
            #pragma unroll
            for (int c = 0; c < 4; ++c)
                qa[c] = *reinterpret_cast<const bf16x8*>(qrow + c * 32 + quad * 8);
        }

        f32x4 o[8];
        #pragma unroll
        for (int f = 0; f < 8; ++f) o[f] = (f32x4){0.f, 0.f, 0.f, 0.f};
        float lrow[4] = {0.f, 0.f, 0.f, 0.f};

        const float* arow = alibi + ((size_t)b * Ss + q0 + quad * 4) * Ss;
        const int ntiles = (q0 + 47) >> 5;      // keys 0..q0+15 (>= 1)

        // prologue: stage tile 0 into buf 0
        {
            const unsigned short* kg = kgbase + (size_t)krow_s * 1024 + (koff_b >> 1);
            GLOAD16(kg,              &kbuf[0][dstw]);
            GLOAD16(kg + 16 * 1024,  &kbuf[0][2048 + dstw]);
            const unsigned short* vg = vt0 + (size_t)vrow_s * Ss + vchk * 8;
            GLOAD16(vg,              &vbuf[0][dstw]);
            GLOAD16(vg + 64 * Ss,    &vbuf[0][2048 + dstw]);
        }
        __syncthreads();

        #pragma unroll 1
        for (int kt = 0; kt < ntiles; ++kt) {
            const int k0  = kt * 32;
            const int cur = kt & 1;

            // --- stage tile t+1 into the other buffer (async, no regs) ---
            if (kt + 1 < ntiles) {
                const int kn = k0 + 32;
                const unsigned short* kg =
                    kgbase + (size_t)(kn + krow_s) * 1024 + (koff_b >> 1);
                GLOAD16(kg,              &kbuf[cur ^ 1][dstw]);
                GLOAD16(kg + 16 * 1024,  &kbuf[cur ^ 1][2048 + dstw]);
                const unsigned short* vg = vt0 + (size_t)vrow_s * Ss + kn + vchk * 8;
                GLOAD16(vg,              &vbuf[cur ^ 1][dstw]);
                GLOAD16(vg + 64 * Ss,    &vbuf[cur ^ 1][2048 + dstw]);
            }

            // --- alibi/mask for this tile (same values in all 4 waves -> L1) ---
            float al0[4], al1[4];
            #pragma unroll
            for (int r = 0; r < 4; ++r) {
                al0[r] = arow[(size_t)r * Ss + k0 + m];
                al1[r] = arow[(size_t)r * Ss + k0 + 16 + m];
            }
            const float am0 = amrow[k0 + m];
            const float am1 = amrow[k0 + 16 + m];

            // --- K fragments from LDS (swizzled read) + QK^T ---
            const char* kb  = (const char*)&kbuf[cur][0];
            const char* vbp = (const char*)&vbuf[cur][0];
            const int  ksw  = (m & 7) << 4;
            bf16x8 kb0[4], kb1[4];
            #pragma unroll
            for (int c = 0; c < 4; ++c) {
                kb0[c] = *(const bf16x8*)(kb + m * 256        + ((c * 64 + quad * 16) ^ ksw));
                kb1[c] = *(const bf16x8*)(kb + (16 + m) * 256 + ((c * 64 + quad * 16) ^ ksw));
            }
            f32x4 s0 = {0.f, 0.f, 0.f, 0.f}, s1 = {0.f, 0.f, 0.f, 0.f};
            #pragma unroll
            for (int c = 0; c < 4; ++c) {
                s0 = __builtin_amdgcn_mfma_f32_16x16x32_bf16(qa[c], kb0[c], s0, 0, 0, 0);
                s1 = __builtin_amdgcn_mfma_f32_16x16x32_bf16(qa[c], kb1[c], s1, 0, 0, 0);
            }

            // --- max-free softmax: p = exp(s + bias) ---
            #pragma unroll
            for (int r = 0; r < 4; ++r) {
                const int qi = q0 + quad * 4 + r;
                float x0 = s0[r] + al0[r] + am0;
                float x1 = s1[r] + al1[r] + am1;
                x0 = (k0 + m      <= qi) ? x0 : -1e30f;
                x1 = (k0 + 16 + m <= qi) ? x1 : -1e30f;
                const float p0 = __expf(x0);
                const float p1 = __expf(x1);
                lrow[r] += p0 + p1;
                s_p[w][quad * 4 + r][m]      = f2bf(p0);
                s_p[w][quad * 4 + r][16 + m] = f2bf(p1);
            }
            // P: C-layout -> A-layout via LDS (same-wave DS is in-order)
            __builtin_amdgcn_wave_barrier();
            const bf16x8 pa = *reinterpret_cast<const bf16x8*>(&s_p[w][m][quad * 8]);
            __builtin_amdgcn_wave_barrier();

            // --- PV from LDS V (linear, at bank floor) ---
            #pragma unroll
            for (int f = 0; f < 8; ++f) {
                const bf16x8 vb = *(const bf16x8*)(vbp + (f * 16 + m) * 64 + quad * 16);
                o[f] = __builtin_amdgcn_mfma_f32_16x16x32_bf16(pa, vb, o[f], 0, 0, 0);
            }

            // drain stage(t+1) + sync buffer reuse (one barrier per tile)
            __syncthreads();
        }

        // reduce l across the 16 columns held by lanes of each quad-row group
        float inv[4];
        #pragma unroll
        for (int r = 0; r < 4; ++r) {
            float l = lrow[r];
            l += __shfl_xor(l, 1, 64);
            l += __shfl_xor(l, 2, 64);
            l += __shfl_xor(l, 4, 64);
            l += __shfl_xor(l, 8, 64);
            inv[r] = 1.f / l;
        }
        #pragma unroll
        for (int f = 0; f < 8; ++f)
            #pragma unroll
            for (int r = 0; r < 4; ++r)
                ctx[(size_t)(b * Ss + q0 + quad * 4 + r) * Dd + h * HDd + f * 16 + m] =
                    f2bf(o[f][r] * inv[r]);
    }
}

extern "C" void kernel_launch(void* const* d_in, const int* in_sizes, int n_in,
                              void* d_out, int out_size, void* d_ws, size_t ws_size,
                              hipStream_t stream) {
    const float* hidden = (const float*)d_in[0];
    const float* cosT   = (const float*)d_in[1];
    const float* sinT   = (const float*)d_in[2];
    const float* alibi  = (const float*)d_in[3];
    const float* amask  = (const float*)d_in[4];
    const float* wq     = (const float*)d_in[5];
    const float* wk     = (const float*)d_in[6];
    const float* wv     = (const float*)d_in[7];
    const float* wo     = (const float*)d_in[8];
    float* out = (float*)d_out;

    char* ws = (char*)d_ws;
    unsigned short* Abf   = (unsigned short*)(ws);              // 16,777,216
    unsigned short* wqT   = (unsigned short*)(ws + 16777216);   //  8,388,608
    unsigned short* kvT   = (unsigned short*)(ws + 25165824);   //  4,194,304
    unsigned short* woT   = (unsigned short*)(ws + 29360128);   //  8,388,608
    unsigned short* Qraw  = (unsigned short*)(ws + 37748736);   // 16,777,216
    unsigned short* KVraw = (unsigned short*)(ws + 54525952);   //  8,388,608
    unsigned short* VT    = (unsigned short*)(ws + 62914560);   //  4,194,304
    unsigned short* Ctx   = (unsigned short*)(ws + 67108864);   // 16,777,216
    // total: 83,886,080 B

    const int M = Bb * Ss;  // 4096

    cast_bf16<<<(M * Dd / 4) / 256, 256, 0, stream>>>(hidden, Abf);
    wt_cast<<<dim3(64, 64), 256, 0, stream>>>(wq, wqT, Dd, Dd);
    wt_cast<<<dim3(64, 16), 256, 0, stream>>>(wk, kvT, Dd, 512);
    wt_cast<<<dim3(64, 16), 256, 0, stream>>>(wv, kvT + (size_t)512 * Dd, Dd, 512);
    wt_cast<<<dim3(64, 64), 256, 0, stream>>>(wo, woT, Dd, Dd);

    gemm_bt<true><<<dim3(Dd / 128, M / 128), 256, 0, stream>>>(Abf, wqT, Qraw, M, Dd, Dd);
    gemm_bt<true><<<dim3(1024 / 128, M / 128), 256, 0, stream>>>(Abf, kvT, KVraw, M, 1024, Dd);

    const float scale = 0.08838834764831845f;  // 1/sqrt(128), folded into Q
    int totQ = Bb * Ss * Hh * 64;
    rope_bf<<<totQ / 256, 256, 0, stream>>>(Qraw, cosT, sinT, 4, Dd, scale, totQ);
    int totK = Bb * Ss * KVHh * 64;
    rope_bf<<<totK / 256, 256, 0, stream>>>(KVraw, cosT, sinT, 2, 1024, 1.0f, totK);

    vt_cast_bf<<<dim3(Ss / 32, HDd / 32, Bb * KVHh), 256, 0, stream>>>(KVraw, VT);

    flash_attn<<<dim3(64, KVHh, Bb), 256, 0, stream>>>(Qraw, KVraw, VT, alibi, amask, Ctx);

    gemm_bt<false><<<dim3(Dd / 128, M / 128), 256, 0, stream>>>(Ctx, woT, out, M, Dd, Dd);
}